// Round 1
// baseline (498.919 us; speedup 1.0000x reference)
//
#include <hip/hip_runtime.h>
#include <stdint.h>

// Problem dims (fixed by the reference)
#define EDIM   1024
#define NHEAD  16
#define DHEAD  64
#define FFDIM  4096
#define SEQLEN 2048
#define NBATCH 2
#define MROWS  (NBATCH * SEQLEN)   // 4096

// MFMA fragment types (per cdna_hip_programming.md §3: short8 = 8 bf16 = 4 VGPRs)
typedef __attribute__((ext_vector_type(8))) short bf16x8;
typedef __attribute__((ext_vector_type(4))) float f32x4;

static __device__ __forceinline__ unsigned short f2bf(float f) {
    union { float f; uint32_t u; } v; v.f = f;
    return (unsigned short)((v.u + 0x7fffu + ((v.u >> 16) & 1u)) >> 16);  // RNE
}

// ---------------- cast f32 -> bf16, 4 elems/thread ----------------
__global__ void k_cast_bf16(const float* __restrict__ in, unsigned short* __restrict__ out, int n4) {
    int i = blockIdx.x * blockDim.x + threadIdx.x;
    if (i < n4) {
        float4 v = ((const float4*)in)[i];
        ushort4 o;
        o.x = f2bf(v.x); o.y = f2bf(v.y); o.z = f2bf(v.z); o.w = f2bf(v.w);
        ((ushort4*)out)[i] = o;
    }
}

// ------------- transpose + cast: in f32 [R][C] -> out bf16 [C][R] -------------
__global__ void k_transpose_cast(const float* __restrict__ in, unsigned short* __restrict__ out,
                                 int R, int C) {
    __shared__ float tile[32][33];
    int c0 = blockIdx.x * 32, r0 = blockIdx.y * 32;
    int tx = threadIdx.x, ty = threadIdx.y;  // block (32,8)
    #pragma unroll
    for (int i = 0; i < 32; i += 8)
        tile[ty + i][tx] = in[(size_t)(r0 + ty + i) * C + c0 + tx];
    __syncthreads();
    #pragma unroll
    for (int i = 0; i < 32; i += 8)
        out[(size_t)(c0 + ty + i) * R + r0 + tx] = f2bf(tile[tx][ty + i]);
}

// ---------------- GEMM: C[M][N] = A[M][K] @ Bt[N][K]^T + bias ----------------
// A, Bt row-major bf16 (Bt is the transposed weight, so both fragment reads are
// contiguous ds_read_b128). EPI: 0 = bf16 out, 1 = gelu->bf16 out, 2 = f32 out.
#define BM 128
#define BN 128
#define BK 64
#define LDT 72   // padded LDS stride (mult of 8 for 16B-aligned b128; 2-way bank alias = free)

template <int EPI>
__global__ __launch_bounds__(256, 2) void k_gemm_bt(
    const unsigned short* __restrict__ A,
    const unsigned short* __restrict__ Bt,
    const float* __restrict__ bias,
    void* __restrict__ Cout, int M, int N, int K)
{
    __shared__ __attribute__((aligned(16))) unsigned short Asm[BM * LDT];
    __shared__ __attribute__((aligned(16))) unsigned short Bsm[BN * LDT];

    const int row0 = blockIdx.y * BM, col0 = blockIdx.x * BN;
    const int t = threadIdx.x;
    const int lane = t & 63, w = t >> 6;
    const int wm = w >> 1, wn = w & 1;           // 2x2 wave grid, each wave 64x64
    const int l15 = lane & 15, l4 = lane >> 4;

    f32x4 acc[4][4];
    #pragma unroll
    for (int m = 0; m < 4; ++m)
        #pragma unroll
        for (int n = 0; n < 4; ++n) acc[m][n] = (f32x4){0.f, 0.f, 0.f, 0.f};

    for (int k0 = 0; k0 < K; k0 += BK) {
        // stage A and Bt tiles: 128x64 bf16 each; 8 chunks of 8 bf16 per row
        #pragma unroll
        for (int it = 0; it < 4; ++it) {
            int idx = it * 256 + t;
            int r = idx >> 3, c = (idx & 7) << 3;
            *(float4*)&Asm[r * LDT + c] = *(const float4*)(A  + (size_t)(row0 + r) * K + k0 + c);
            *(float4*)&Bsm[r * LDT + c] = *(const float4*)(Bt + (size_t)(col0 + r) * K + k0 + c);
        }
        __syncthreads();
        #pragma unroll
        for (int kk = 0; kk < BK; kk += 32) {
            bf16x8 af[4], bf[4];
            #pragma unroll
            for (int m = 0; m < 4; ++m)
                af[m] = *(const bf16x8*)&Asm[(wm * 64 + m * 16 + l15) * LDT + kk + l4 * 8];
            #pragma unroll
            for (int n = 0; n < 4; ++n)
                bf[n] = *(const bf16x8*)&Bsm[(wn * 64 + n * 16 + l15) * LDT + kk + l4 * 8];
            #pragma unroll
            for (int m = 0; m < 4; ++m)
                #pragma unroll
                for (int n = 0; n < 4; ++n)
                    acc[m][n] = __builtin_amdgcn_mfma_f32_16x16x32_bf16(af[m], bf[n], acc[m][n], 0, 0, 0);
        }
        __syncthreads();
    }

    // epilogue: C/D layout (m89-verified): row = (lane>>4)*4 + i, col = lane&15
    #pragma unroll
    for (int m = 0; m < 4; ++m) {
        int rb = row0 + wm * 64 + m * 16 + l4 * 4;
        #pragma unroll
        for (int n = 0; n < 4; ++n) {
            int c = col0 + wn * 64 + n * 16 + l15;
            float bv = bias[c];
            #pragma unroll
            for (int i = 0; i < 4; ++i) {
                float v = acc[m][n][i] + bv;
                if (EPI == 1) v = 0.5f * v * (1.0f + erff(v * 0.70710678118654752f));
                if (EPI == 2) ((float*)Cout)[(size_t)(rb + i) * N + c] = v;
                else          ((unsigned short*)Cout)[(size_t)(rb + i) * N + c] = f2bf(v);
            }
        }
    }
}

// ---------------- flash attention ----------------
// grid (SEQLEN/64, NBATCH*NHEAD), block 256 (4 waves; wave w owns q-rows [w*16, w*16+16))
__global__ __launch_bounds__(256, 2) void k_attn(
    const unsigned short* __restrict__ Qb,
    const unsigned short* __restrict__ Kb,
    const unsigned short* __restrict__ Vb,
    const float* __restrict__ pbias,   // [H][S][S]
    const float* __restrict__ mask,    // [B][S]
    unsigned short* __restrict__ Ctx)  // [B*S][E]
{
    __shared__ __attribute__((aligned(16))) unsigned short Ksm[64 * 72];  // [t][d]
    __shared__ __attribute__((aligned(16))) unsigned short Vsm[64 * 72];  // transposed [d][t]
    __shared__ __attribute__((aligned(16))) unsigned short Psm[64 * 72];  // [qrow][t] per-wave slices

    const int bh = blockIdx.y;
    const int b = bh / NHEAD, h = bh % NHEAD;
    const int q0 = blockIdx.x * 64;
    const int t = threadIdx.x;
    const int lane = t & 63, w = t >> 6;
    const int l15 = lane & 15, l4 = lane >> 4;

    // Q fragments live in registers for the whole kernel
    bf16x8 qf0, qf1;
    {
        const unsigned short* qp = Qb + (size_t)(b * SEQLEN + q0 + w * 16 + l15) * EDIM + h * DHEAD + l4 * 8;
        qf0 = *(const bf16x8*)qp;
        qf1 = *(const bf16x8*)(qp + 32);
    }

    f32x4 oacc[4];  // [dh-block][i]
    #pragma unroll
    for (int nd = 0; nd < 4; ++nd) oacc[nd] = (f32x4){0.f, 0.f, 0.f, 0.f};
    float m_run[4] = {-1e30f, -1e30f, -1e30f, -1e30f};
    float l_run[4] = {0.f, 0.f, 0.f, 0.f};
    const int srow0 = q0 + w * 16 + l4 * 4;

    for (int kt = 0; kt < SEQLEN / 64; ++kt) {
        const size_t kvbase = (size_t)(b * SEQLEN + kt * 64) * EDIM + h * DHEAD;
        #pragma unroll
        for (int it = 0; it < 2; ++it) {
            int idx = it * 256 + t;
            int r = idx >> 3, c = (idx & 7) << 3;
            *(float4*)&Ksm[r * 72 + c] = *(const float4*)(Kb + kvbase + (size_t)r * EDIM + c);
            float4 vv = *(const float4*)(Vb + kvbase + (size_t)r * EDIM + c);
            const unsigned short* vp = (const unsigned short*)&vv;
            #pragma unroll
            for (int e = 0; e < 8; ++e) Vsm[(c + e) * 72 + r] = vp[e];  // transpose-on-store
        }
        __syncthreads();

        // QK^T for 64 keys: scores row=(l4*4+i), col=(n*16+l15)
        float p[4][4];  // [n][i]
        float tmax[4] = {-1e30f, -1e30f, -1e30f, -1e30f};
        #pragma unroll
        for (int n = 0; n < 4; ++n) {
            bf16x8 kb0 = *(const bf16x8*)&Ksm[(n * 16 + l15) * 72 + l4 * 8];
            bf16x8 kb1 = *(const bf16x8*)&Ksm[(n * 16 + l15) * 72 + 32 + l4 * 8];
            f32x4 z = (f32x4){0.f, 0.f, 0.f, 0.f};
            z = __builtin_amdgcn_mfma_f32_16x16x32_bf16(qf0, kb0, z, 0, 0, 0);
            z = __builtin_amdgcn_mfma_f32_16x16x32_bf16(qf1, kb1, z, 0, 0, 0);
            const int scol = kt * 64 + n * 16 + l15;
            const float mk = mask[b * SEQLEN + scol];
            const float* pb = pbias + ((size_t)h * SEQLEN + srow0) * SEQLEN + scol;
            #pragma unroll
            for (int i = 0; i < 4; ++i) {
                float v = z[i] * 0.125f + pb[(size_t)i * SEQLEN] + mk;
                p[n][i] = v;
                tmax[i] = fmaxf(tmax[i], v);
            }
        }
        // online softmax: row-reduce across the 16-lane group (same l4)
        #pragma unroll
        for (int i = 0; i < 4; ++i) {
            float mv = tmax[i];
            #pragma unroll
            for (int off = 1; off < 16; off <<= 1) mv = fmaxf(mv, __shfl_xor(mv, off, 64));
            float mnew = fmaxf(m_run[i], mv);
            float alpha = __expf(m_run[i] - mnew);
            m_run[i] = mnew;
            float sum = 0.f;
            #pragma unroll
            for (int n = 0; n < 4; ++n) { p[n][i] = __expf(p[n][i] - mnew); sum += p[n][i]; }
            #pragma unroll
            for (int off = 1; off < 16; off <<= 1) sum += __shfl_xor(sum, off, 64);
            l_run[i] = l_run[i] * alpha + sum;
            #pragma unroll
            for (int nd = 0; nd < 4; ++nd) oacc[nd][i] *= alpha;
        }
        // P -> LDS (per-wave private rows, no barrier needed)
        #pragma unroll
        for (int n = 0; n < 4; ++n)
            #pragma unroll
            for (int i = 0; i < 4; ++i)
                Psm[(w * 16 + l4 * 4 + i) * 72 + n * 16 + l15] = f2bf(p[n][i]);
        // PV: O += P @ V
        #pragma unroll
        for (int kk = 0; kk < 2; ++kk) {
            bf16x8 pa = *(const bf16x8*)&Psm[(w * 16 + l15) * 72 + kk * 32 + l4 * 8];
            #pragma unroll
            for (int nd = 0; nd < 4; ++nd) {
                bf16x8 vf = *(const bf16x8*)&Vsm[(nd * 16 + l15) * 72 + kk * 32 + l4 * 8];
                oacc[nd] = __builtin_amdgcn_mfma_f32_16x16x32_bf16(pa, vf, oacc[nd], 0, 0, 0);
            }
        }
        __syncthreads();  // protect Ksm/Vsm before next stage
    }

    #pragma unroll
    for (int nd = 0; nd < 4; ++nd)
        #pragma unroll
        for (int i = 0; i < 4; ++i) {
            float v = oacc[nd][i] / l_run[i];
            Ctx[(size_t)(b * SEQLEN + q0 + w * 16 + l4 * 4 + i) * EDIM + h * DHEAD + nd * 16 + l15] = f2bf(v);
        }
}

// ---------------- LayerNorm over E=1024: out = LN(X + T)*g + b ----------------
template <int WRITE_BF>
__global__ __launch_bounds__(256) void k_ln(
    const float* __restrict__ X, const float* __restrict__ T,
    const float* __restrict__ gam, const float* __restrict__ bet,
    float* __restrict__ Of, unsigned short* __restrict__ Ob)
{
    const int r = blockIdx.x;
    const int t = threadIdx.x;
    const size_t base = (size_t)r * EDIM + t * 4;
    float4 xv = *(const float4*)(X + base);
    float4 tv = *(const float4*)(T + base);
    float4 s = make_float4(xv.x + tv.x, xv.y + tv.y, xv.z + tv.z, xv.w + tv.w);
    float sum = s.x + s.y + s.z + s.w;
    float sq  = s.x * s.x + s.y * s.y + s.z * s.z + s.w * s.w;
    #pragma unroll
    for (int off = 1; off < 64; off <<= 1) {
        sum += __shfl_xor(sum, off, 64);
        sq  += __shfl_xor(sq,  off, 64);
    }
    __shared__ float red[8];
    const int lane = t & 63, w = t >> 6;
    if (lane == 0) { red[w] = sum; red[4 + w] = sq; }
    __syncthreads();
    sum = red[0] + red[1] + red[2] + red[3];
    sq  = red[4] + red[5] + red[6] + red[7];
    const float mu = sum * (1.0f / EDIM);
    const float var = sq * (1.0f / EDIM) - mu * mu;
    const float rs = rsqrtf(var + 1e-5f);
    float4 gv = *(const float4*)(gam + t * 4);
    float4 bv = *(const float4*)(bet + t * 4);
    float4 o = make_float4((s.x - mu) * rs * gv.x + bv.x,
                           (s.y - mu) * rs * gv.y + bv.y,
                           (s.z - mu) * rs * gv.z + bv.z,
                           (s.w - mu) * rs * gv.w + bv.w);
    *(float4*)(Of + base) = o;
    if (WRITE_BF) {
        ushort4 ob;
        ob.x = f2bf(o.x); ob.y = f2bf(o.y); ob.z = f2bf(o.z); ob.w = f2bf(o.w);
        *(ushort4*)(Ob + base) = ob;
    }
}

extern "C" void kernel_launch(void* const* d_in, const int* in_sizes, int n_in,
                              void* d_out, int out_size, void* d_ws, size_t ws_size,
                              hipStream_t stream) {
    const float* x    = (const float*)d_in[0];
    const float* mask = (const float*)d_in[1];
    const float* pb   = (const float*)d_in[2];
    const float* Wq = (const float*)d_in[3];  const float* bq = (const float*)d_in[4];
    const float* Wk = (const float*)d_in[5];  const float* bk = (const float*)d_in[6];
    const float* Wv = (const float*)d_in[7];  const float* bv = (const float*)d_in[8];
    const float* Wo = (const float*)d_in[9];  const float* bo = (const float*)d_in[10];
    const float* g1 = (const float*)d_in[11]; const float* be1 = (const float*)d_in[12];
    const float* W1 = (const float*)d_in[13]; const float* b1 = (const float*)d_in[14];
    const float* W2 = (const float*)d_in[15]; const float* b2 = (const float*)d_in[16];
    const float* g2 = (const float*)d_in[17]; const float* be2 = (const float*)d_in[18];
    float* out = (float*)d_out;

    // workspace layout (104 MB total); region [0,32MB) holds xb/q/k/v, then is
    // reused for the FFN intermediate (they are dead by FFN1 time)
    char* ws = (char*)d_ws;
    const size_t MB = 1024 * 1024;
    unsigned short* xb   = (unsigned short*)(ws + 0);        // 8 MB
    unsigned short* qb   = (unsigned short*)(ws + 8  * MB);  // 8 MB
    unsigned short* kb   = (unsigned short*)(ws + 16 * MB);  // 8 MB
    unsigned short* vb   = (unsigned short*)(ws + 24 * MB);  // 8 MB
    unsigned short* gbf  = (unsigned short*)(ws + 0);        // 32 MB alias (FFN mid)
    unsigned short* wqt  = (unsigned short*)(ws + 32 * MB);  // 2 MB
    unsigned short* wkt  = (unsigned short*)(ws + 34 * MB);
    unsigned short* wvt  = (unsigned short*)(ws + 36 * MB);
    unsigned short* wot  = (unsigned short*)(ws + 38 * MB);
    unsigned short* w1t  = (unsigned short*)(ws + 40 * MB);  // 8 MB  [FF][E]
    unsigned short* w2t  = (unsigned short*)(ws + 48 * MB);  // 8 MB  [E][FF]
    unsigned short* ctxb = (unsigned short*)(ws + 56 * MB);  // 8 MB
    float*          t1   = (float*)(ws + 64 * MB);           // 16 MB (attn out, reused for ffn out)
    float*          hf   = (float*)(ws + 80 * MB);           // 16 MB
    unsigned short* hb   = (unsigned short*)(ws + 96 * MB);  // 8 MB

    const dim3 b256(256);
    const dim3 tb(32, 8);

    k_cast_bf16<<<dim3(MROWS * EDIM / 4 / 256), b256, 0, stream>>>(x, xb, MROWS * EDIM / 4);
    k_transpose_cast<<<dim3(EDIM / 32, EDIM / 32), tb, 0, stream>>>(Wq, wqt, EDIM, EDIM);
    k_transpose_cast<<<dim3(EDIM / 32, EDIM / 32), tb, 0, stream>>>(Wk, wkt, EDIM, EDIM);
    k_transpose_cast<<<dim3(EDIM / 32, EDIM / 32), tb, 0, stream>>>(Wv, wvt, EDIM, EDIM);
    k_transpose_cast<<<dim3(EDIM / 32, EDIM / 32), tb, 0, stream>>>(Wo, wot, EDIM, EDIM);
    k_transpose_cast<<<dim3(FFDIM / 32, EDIM / 32), tb, 0, stream>>>(W1, w1t, EDIM, FFDIM);
    k_transpose_cast<<<dim3(EDIM / 32, FFDIM / 32), tb, 0, stream>>>(W2, w2t, FFDIM, EDIM);

    k_gemm_bt<0><<<dim3(EDIM / BN, MROWS / BM), b256, 0, stream>>>(xb, wqt, bq, qb, MROWS, EDIM, EDIM);
    k_gemm_bt<0><<<dim3(EDIM / BN, MROWS / BM), b256, 0, stream>>>(xb, wkt, bk, kb, MROWS, EDIM, EDIM);
    k_gemm_bt<0><<<dim3(EDIM / BN, MROWS / BM), b256, 0, stream>>>(xb, wvt, bv, vb, MROWS, EDIM, EDIM);

    k_attn<<<dim3(SEQLEN / 64, NBATCH * NHEAD), b256, 0, stream>>>(qb, kb, vb, pb, mask, ctxb);

    k_gemm_bt<2><<<dim3(EDIM / BN, MROWS / BM), b256, 0, stream>>>(ctxb, wot, bo, t1, MROWS, EDIM, EDIM);
    k_ln<1><<<dim3(MROWS), b256, 0, stream>>>(x, t1, g1, be1, hf, hb);
    k_gemm_bt<1><<<dim3(FFDIM / BN, MROWS / BM), b256, 0, stream>>>(hb, w1t, b1, gbf, MROWS, FFDIM, EDIM);
    k_gemm_bt<2><<<dim3(EDIM / BN, MROWS / BM), b256, 0, stream>>>(gbf, w2t, b2, t1, MROWS, EDIM, FFDIM);
    k_ln<0><<<dim3(MROWS), b256, 0, stream>>>(hf, t1, g2, be2, out, nullptr);
    (void)in_sizes; (void)n_in; (void)out_size; (void)ws_size;
}

// Round 2
// 420.653 us; speedup vs baseline: 1.1861x; 1.1861x over previous
//
#include <hip/hip_runtime.h>
#include <stdint.h>

#define EDIM   1024
#define NHEAD  16
#define DHEAD  64
#define FFDIM  4096
#define SEQLEN 2048
#define NBATCH 2
#define MROWS  (NBATCH * SEQLEN)   // 4096

typedef __attribute__((ext_vector_type(8))) short bf16x8;
typedef __attribute__((ext_vector_type(4))) float f32x4;

static __device__ __forceinline__ unsigned short f2bf(float f) {
    union { float f; uint32_t u; } v; v.f = f;
    return (unsigned short)((v.u + 0x7fffu + ((v.u >> 16) & 1u)) >> 16);  // RNE
}

// async global->LDS, 16B per lane; LDS dest = wave-uniform base + lane*16
static __device__ __forceinline__ void gload16(const void* g, void* s) {
    __builtin_amdgcn_global_load_lds(
        (const __attribute__((address_space(1))) unsigned int*)g,
        (__attribute__((address_space(3))) unsigned int*)s,
        16, 0, 0);
}

// ---------------- cast f32 -> bf16 ----------------
__global__ void k_cast_bf16(const float* __restrict__ in, unsigned short* __restrict__ out, int n4) {
    int i = blockIdx.x * blockDim.x + threadIdx.x;
    if (i < n4) {
        float4 v = ((const float4*)in)[i];
        ushort4 o;
        o.x = f2bf(v.x); o.y = f2bf(v.y); o.z = f2bf(v.z); o.w = f2bf(v.w);
        ((ushort4*)out)[i] = o;
    }
}

// ------------- transpose + cast: in f32 [R][C] -> out bf16 [C][R] -------------
__global__ void k_transpose_cast(const float* __restrict__ in, unsigned short* __restrict__ out,
                                 int R, int C) {
    __shared__ float tile[32][33];
    int c0 = blockIdx.x * 32, r0 = blockIdx.y * 32;
    int tx = threadIdx.x, ty = threadIdx.y;  // block (32,8)
    #pragma unroll
    for (int i = 0; i < 32; i += 8)
        tile[ty + i][tx] = in[(size_t)(r0 + ty + i) * C + c0 + tx];
    __syncthreads();
    #pragma unroll
    for (int i = 0; i < 32; i += 8)
        out[(size_t)(c0 + ty + i) * R + r0 + tx] = f2bf(tile[tx][ty + i]);
}

// ------------- per-head V transpose: V[b*S+s][h*64+d] -> Vt[(b*16+h)*64+d][s] -------------
__global__ void k_transpose_v(const unsigned short* __restrict__ V, int vstride,
                              unsigned short* __restrict__ Vt) {
    __shared__ unsigned short tile[32][33];
    const int bh = blockIdx.z, b = bh >> 4, h = bh & 15;
    const int s0 = blockIdx.x * 32, d0 = blockIdx.y * 32;
    const int tx = threadIdx.x, ty = threadIdx.y;  // block (32,8)
    #pragma unroll
    for (int i = 0; i < 32; i += 8)
        tile[ty + i][tx] = V[(size_t)(b * SEQLEN + s0 + ty + i) * vstride + h * DHEAD + d0 + tx];
    __syncthreads();
    #pragma unroll
    for (int i = 0; i < 32; i += 8)
        Vt[((size_t)(b * NHEAD + h) * DHEAD + d0 + ty + i) * SEQLEN + s0 + tx] = tile[tx][ty + i];
}

__global__ void k_concat_bias(const float* __restrict__ bq, const float* __restrict__ bk,
                              const float* __restrict__ bv, float* __restrict__ out) {
    int i = blockIdx.x * 256 + threadIdx.x;  // 0..3071
    const float* src = (i < 1024) ? bq : (i < 2048) ? bk : bv;
    out[i] = src[i & 1023];
}

// ---------------- GEMM (m97 structure): C[M][N] = A[M][K] @ Bt[N][K]^T + bias ----------------
// linear (unpadded) LDS tiles filled by global_load_lds width=16.
// EPI: 0 = bf16 out, 1 = gelu->bf16 out, 2 = f32 out.
template <int TBM, int TBN, int EPI>
__global__ __launch_bounds__(256, 2) void k_gemm(
    const unsigned short* __restrict__ A,
    const unsigned short* __restrict__ Bt,
    const float* __restrict__ bias,
    void* __restrict__ Cout, int M, int N, int K)
{
    constexpr int MR = TBM / 32, NR = TBN / 32;
    __shared__ __attribute__((aligned(16))) unsigned short Asm[TBM * 64];
    __shared__ __attribute__((aligned(16))) unsigned short Bsm[TBN * 64];

    const int row0 = blockIdx.y * TBM, col0 = blockIdx.x * TBN;
    const int t = threadIdx.x;
    const int lane = t & 63, w = t >> 6;
    const int wm = w >> 1, wn = w & 1;          // 2x2 wave grid
    const int l15 = lane & 15, l4 = lane >> 4;
    const int sr = lane >> 3, sc = (lane & 7) * 8;   // staging lane map (8 rows x 128B)

    f32x4 acc[MR][NR];
    #pragma unroll
    for (int m = 0; m < MR; ++m)
        #pragma unroll
        for (int n = 0; n < NR; ++n) acc[m][n] = (f32x4){0.f, 0.f, 0.f, 0.f};

    for (int k0 = 0; k0 < K; k0 += 64) {
        #pragma unroll
        for (int i = 0; i < TBM / 32; ++i) {
            const int r = w * (TBM / 4) + i * 8;   // wave-uniform chunk base row
            gload16(A + (size_t)(row0 + r + sr) * K + k0 + sc, &Asm[r * 64]);
        }
        #pragma unroll
        for (int i = 0; i < TBN / 32; ++i) {
            const int r = w * (TBN / 4) + i * 8;
            gload16(Bt + (size_t)(col0 + r + sr) * K + k0 + sc, &Bsm[r * 64]);
        }
        __syncthreads();
        #pragma unroll
        for (int kk = 0; kk < 64; kk += 32) {
            bf16x8 af[MR], bf[NR];
            #pragma unroll
            for (int m = 0; m < MR; ++m)
                af[m] = *(const bf16x8*)&Asm[(wm * (TBM / 2) + m * 16 + l15) * 64 + kk + l4 * 8];
            #pragma unroll
            for (int n = 0; n < NR; ++n)
                bf[n] = *(const bf16x8*)&Bsm[(wn * (TBN / 2) + n * 16 + l15) * 64 + kk + l4 * 8];
            #pragma unroll
            for (int m = 0; m < MR; ++m)
                #pragma unroll
                for (int n = 0; n < NR; ++n)
                    acc[m][n] = __builtin_amdgcn_mfma_f32_16x16x32_bf16(af[m], bf[n], acc[m][n], 0, 0, 0);
        }
        __syncthreads();
    }

    #pragma unroll
    for (int m = 0; m < MR; ++m) {
        int rb = row0 + wm * (TBM / 2) + m * 16 + l4 * 4;
        #pragma unroll
        for (int n = 0; n < NR; ++n) {
            int c = col0 + wn * (TBN / 2) + n * 16 + l15;
            float bv = bias[c];
            #pragma unroll
            for (int i = 0; i < 4; ++i) {
                float v = acc[m][n][i] + bv;
                if (EPI == 1) v = 0.5f * v * (1.0f + erff(v * 0.70710678118654752f));
                if (EPI == 2) ((float*)Cout)[(size_t)(rb + i) * N + c] = v;
                else          ((unsigned short*)Cout)[(size_t)(rb + i) * N + c] = f2bf(v);
            }
        }
    }
}

// ---------------- flash attention, both batches per block ----------------
// grid (NHEAD, SEQLEN/64), block 512 (8 waves). Wave w: batch = w&1, q-rows = (w>>1)*16..+16.
__global__ __launch_bounds__(512, 2) void k_attn(
    const unsigned short* __restrict__ QKV,  // [B*S][3E]: q at +0, k at +E
    const unsigned short* __restrict__ Vt,   // [(b*16+h)*64 + d][S]
    const float* __restrict__ pbias,         // [H][S][S]
    const float* __restrict__ mask,          // [B][S]
    unsigned short* __restrict__ Ctx)        // [B*S][E]
{
    __shared__ __attribute__((aligned(16))) unsigned short Ksm[2][64 * 72];
    __shared__ __attribute__((aligned(16))) unsigned short Vsm[2][64 * 72];  // [d][t]
    __shared__ __attribute__((aligned(16))) unsigned short Psm[128 * 72];

    const int h = blockIdx.x;            // h fastest -> same-h blocks share XCD L2
    const int q0 = blockIdx.y * 64;
    const int t = threadIdx.x;
    const int lane = t & 63, w = t >> 6;
    const int wb = w & 1;                // batch
    const int wq = (w >> 1) * 16;        // q-row block within tile
    const int l15 = lane & 15, l4 = lane >> 4;

    bf16x8 qf0, qf1;
    {
        const unsigned short* qp = QKV + (size_t)(wb * SEQLEN + q0 + wq + l15) * (3 * EDIM) + h * DHEAD + l4 * 8;
        qf0 = *(const bf16x8*)qp;
        qf1 = *(const bf16x8*)(qp + 32);
    }

    f32x4 oacc[4];
    #pragma unroll
    for (int nd = 0; nd < 4; ++nd) oacc[nd] = (f32x4){0.f, 0.f, 0.f, 0.f};
    float m_run[4] = {-1e30f, -1e30f, -1e30f, -1e30f};
    float l_run[4] = {0.f, 0.f, 0.f, 0.f};
    const int srow0 = q0 + wq + l4 * 4;
    const float* pbrow = pbias + ((size_t)h * SEQLEN + srow0) * SEQLEN;

    for (int kt = 0; kt < SEQLEN / 64; ++kt) {
        // ---- stage K (both b) and Vt (both b), all float4 ----
        #pragma unroll
        for (int j = 0; j < 4; ++j) {
            int cid = j * 512 + t;
            int tile = cid >> 9;           // wave-uniform
            int r = (cid >> 3) & 63;
            int c = (cid & 7) * 8;
            int bb = tile & 1;
            if (tile < 2)
                *(float4*)&Ksm[bb][r * 72 + c] =
                    *(const float4*)(QKV + (size_t)(bb * SEQLEN + kt * 64 + r) * (3 * EDIM) + EDIM + h * DHEAD + c);
            else
                *(float4*)&Vsm[bb][r * 72 + c] =
                    *(const float4*)(Vt + ((size_t)((bb * NHEAD + h) * DHEAD + r)) * SEQLEN + kt * 64 + c);
        }
        __syncthreads();

        // ---- pbias + mask into registers (shared across this wave's batch) ----
        float pbv[4][4], mkv[4];
        #pragma unroll
        for (int n = 0; n < 4; ++n) {
            const int scol = kt * 64 + n * 16 + l15;
            mkv[n] = mask[wb * SEQLEN + scol];
            #pragma unroll
            for (int i = 0; i < 4; ++i)
                pbv[n][i] = pbrow[(size_t)i * SEQLEN + scol];
        }

        // ---- QK^T ----
        float p[4][4];
        float tmax[4] = {-1e30f, -1e30f, -1e30f, -1e30f};
        #pragma unroll
        for (int n = 0; n < 4; ++n) {
            bf16x8 kb0 = *(const bf16x8*)&Ksm[wb][(n * 16 + l15) * 72 + l4 * 8];
            bf16x8 kb1 = *(const bf16x8*)&Ksm[wb][(n * 16 + l15) * 72 + 32 + l4 * 8];
            f32x4 z = (f32x4){0.f, 0.f, 0.f, 0.f};
            z = __builtin_amdgcn_mfma_f32_16x16x32_bf16(qf0, kb0, z, 0, 0, 0);
            z = __builtin_amdgcn_mfma_f32_16x16x32_bf16(qf1, kb1, z, 0, 0, 0);
            #pragma unroll
            for (int i = 0; i < 4; ++i) {
                float v = z[i] * 0.125f + pbv[n][i] + mkv[n];
                p[n][i] = v;
                tmax[i] = fmaxf(tmax[i], v);
            }
        }
        // ---- online softmax (16-lane row groups) ----
        #pragma unroll
        for (int i = 0; i < 4; ++i) {
            float mv = tmax[i];
            #pragma unroll
            for (int off = 1; off < 16; off <<= 1) mv = fmaxf(mv, __shfl_xor(mv, off, 64));
            float mnew = fmaxf(m_run[i], mv);
            float alpha = __expf(m_run[i] - mnew);
            m_run[i] = mnew;
            float sum = 0.f;
            #pragma unroll
            for (int n = 0; n < 4; ++n) { p[n][i] = __expf(p[n][i] - mnew); sum += p[n][i]; }
            #pragma unroll
            for (int off = 1; off < 16; off <<= 1) sum += __shfl_xor(sum, off, 64);
            l_run[i] = l_run[i] * alpha + sum;
            #pragma unroll
            for (int nd = 0; nd < 4; ++nd) oacc[nd][i] *= alpha;
        }
        // ---- P -> LDS (wave-private rows), PV ----
        #pragma unroll
        for (int n = 0; n < 4; ++n)
            #pragma unroll
            for (int i = 0; i < 4; ++i)
                Psm[(w * 16 + l4 * 4 + i) * 72 + n * 16 + l15] = f2bf(p[n][i]);
        #pragma unroll
        for (int kk = 0; kk < 2; ++kk) {
            bf16x8 pa = *(const bf16x8*)&Psm[(w * 16 + l15) * 72 + kk * 32 + l4 * 8];
            #pragma unroll
            for (int nd = 0; nd < 4; ++nd) {
                bf16x8 vf = *(const bf16x8*)&Vsm[wb][(nd * 16 + l15) * 72 + kk * 32 + l4 * 8];
                oacc[nd] = __builtin_amdgcn_mfma_f32_16x16x32_bf16(pa, vf, oacc[nd], 0, 0, 0);
            }
        }
        __syncthreads();
    }

    #pragma unroll
    for (int nd = 0; nd < 4; ++nd)
        #pragma unroll
        for (int i = 0; i < 4; ++i) {
            float v = oacc[nd][i] / l_run[i];
            Ctx[(size_t)(wb * SEQLEN + q0 + wq + l4 * 4 + i) * EDIM + h * DHEAD + nd * 16 + l15] = f2bf(v);
        }
}

// ---------------- LayerNorm over E=1024: out = LN(X + T)*g + b ----------------
template <int WRITE_BF>
__global__ __launch_bounds__(256) void k_ln(
    const float* __restrict__ X, const float* __restrict__ T,
    const float* __restrict__ gam, const float* __restrict__ bet,
    float* __restrict__ Of, unsigned short* __restrict__ Ob)
{
    const int r = blockIdx.x;
    const int t = threadIdx.x;
    const size_t base = (size_t)r * EDIM + t * 4;
    float4 xv = *(const float4*)(X + base);
    float4 tv = *(const float4*)(T + base);
    float4 s = make_float4(xv.x + tv.x, xv.y + tv.y, xv.z + tv.z, xv.w + tv.w);
    float sum = s.x + s.y + s.z + s.w;
    float sq  = s.x * s.x + s.y * s.y + s.z * s.z + s.w * s.w;
    #pragma unroll
    for (int off = 1; off < 64; off <<= 1) {
        sum += __shfl_xor(sum, off, 64);
        sq  += __shfl_xor(sq,  off, 64);
    }
    __shared__ float red[8];
    const int lane = t & 63, w = t >> 6;
    if (lane == 0) { red[w] = sum; red[4 + w] = sq; }
    __syncthreads();
    sum = red[0] + red[1] + red[2] + red[3];
    sq  = red[4] + red[5] + red[6] + red[7];
    const float mu = sum * (1.0f / EDIM);
    const float var = sq * (1.0f / EDIM) - mu * mu;
    const float rs = rsqrtf(var + 1e-5f);
    float4 gv = *(const float4*)(gam + t * 4);
    float4 bv = *(const float4*)(bet + t * 4);
    float4 o = make_float4((s.x - mu) * rs * gv.x + bv.x,
                           (s.y - mu) * rs * gv.y + bv.y,
                           (s.z - mu) * rs * gv.z + bv.z,
                           (s.w - mu) * rs * gv.w + bv.w);
    *(float4*)(Of + base) = o;
    if (WRITE_BF) {
        ushort4 ob;
        ob.x = f2bf(o.x); ob.y = f2bf(o.y); ob.z = f2bf(o.z); ob.w = f2bf(o.w);
        *(ushort4*)(Ob + base) = ob;
    }
}

extern "C" void kernel_launch(void* const* d_in, const int* in_sizes, int n_in,
                              void* d_out, int out_size, void* d_ws, size_t ws_size,
                              hipStream_t stream) {
    const float* x    = (const float*)d_in[0];
    const float* mask = (const float*)d_in[1];
    const float* pb   = (const float*)d_in[2];
    const float* Wq = (const float*)d_in[3];  const float* bq = (const float*)d_in[4];
    const float* Wk = (const float*)d_in[5];  const float* bk = (const float*)d_in[6];
    const float* Wv = (const float*)d_in[7];  const float* bv = (const float*)d_in[8];
    const float* Wo = (const float*)d_in[9];  const float* bo = (const float*)d_in[10];
    const float* g1 = (const float*)d_in[11]; const float* be1 = (const float*)d_in[12];
    const float* W1 = (const float*)d_in[13]; const float* b1 = (const float*)d_in[14];
    const float* W2 = (const float*)d_in[15]; const float* b2 = (const float*)d_in[16];
    const float* g2 = (const float*)d_in[17]; const float* be2 = (const float*)d_in[18];
    float* out = (float*)d_out;

    // workspace layout (104 MB, same footprint as round 1)
    //  +0   qkv  bf16 [4096][3072]  24 MB   (aliased later by gbf 32 MB)
    //  +24  xb   bf16 [4096][1024]   8 MB   (dead after QKV GEMM; reused as Vt)
    //  +32  wqt/wkt/wvt (contiguous = fused Bt[3072][1024]) 6 MB, +38 wot 2 MB
    //  +40  w1t 8 MB, +48 w2t 8 MB
    //  +56  bcat (12 KB, dead before ctxb) / ctxb bf16 8 MB
    //  +64  t1 f32 16 MB, +80 hf f32 16 MB, +96 hb bf16 8 MB
    char* ws = (char*)d_ws;
    const size_t MB = 1024 * 1024;
    unsigned short* qkv  = (unsigned short*)(ws + 0);
    unsigned short* gbf  = (unsigned short*)(ws + 0);
    unsigned short* xb   = (unsigned short*)(ws + 24 * MB);
    unsigned short* vt   = (unsigned short*)(ws + 24 * MB);
    unsigned short* wqt  = (unsigned short*)(ws + 32 * MB);
    unsigned short* wkt  = (unsigned short*)(ws + 34 * MB);
    unsigned short* wvt  = (unsigned short*)(ws + 36 * MB);
    unsigned short* wot  = (unsigned short*)(ws + 38 * MB);
    unsigned short* w1t  = (unsigned short*)(ws + 40 * MB);
    unsigned short* w2t  = (unsigned short*)(ws + 48 * MB);
    float*          bcat = (float*)(ws + 56 * MB);
    unsigned short* ctxb = (unsigned short*)(ws + 56 * MB);
    float*          t1   = (float*)(ws + 64 * MB);
    float*          hf   = (float*)(ws + 80 * MB);
    unsigned short* hb   = (unsigned short*)(ws + 96 * MB);

    const dim3 b256(256);
    const dim3 tb(32, 8);

    k_cast_bf16<<<dim3(MROWS * EDIM / 4 / 256), b256, 0, stream>>>(x, xb, MROWS * EDIM / 4);
    k_transpose_cast<<<dim3(EDIM / 32, EDIM / 32), tb, 0, stream>>>(Wq, wqt, EDIM, EDIM);
    k_transpose_cast<<<dim3(EDIM / 32, EDIM / 32), tb, 0, stream>>>(Wk, wkt, EDIM, EDIM);
    k_transpose_cast<<<dim3(EDIM / 32, EDIM / 32), tb, 0, stream>>>(Wv, wvt, EDIM, EDIM);
    k_transpose_cast<<<dim3(EDIM / 32, EDIM / 32), tb, 0, stream>>>(Wo, wot, EDIM, EDIM);
    k_transpose_cast<<<dim3(FFDIM / 32, EDIM / 32), tb, 0, stream>>>(W1, w1t, EDIM, FFDIM);
    k_transpose_cast<<<dim3(EDIM / 32, FFDIM / 32), tb, 0, stream>>>(W2, w2t, FFDIM, EDIM);
    k_concat_bias<<<dim3(12), b256, 0, stream>>>(bq, bk, bv, bcat);

    // fused QKV: [4096][3072]
    k_gemm<128, 128, 0><<<dim3(3 * EDIM / 128, MROWS / 128), b256, 0, stream>>>(
        xb, wqt, bcat, qkv, MROWS, 3 * EDIM, EDIM);
    // V^T per head (input = qkv v-slice, stride 3072)
    k_transpose_v<<<dim3(SEQLEN / 32, DHEAD / 32, NBATCH * NHEAD), tb, 0, stream>>>(
        qkv + 2 * EDIM, 3 * EDIM, vt);

    k_attn<<<dim3(NHEAD, SEQLEN / 64), dim3(512), 0, stream>>>(qkv, vt, pb, mask, ctxb);

    k_gemm<128, 64, 2><<<dim3(EDIM / 64, MROWS / 128), b256, 0, stream>>>(
        ctxb, wot, bo, t1, MROWS, EDIM, EDIM);
    k_ln<1><<<dim3(MROWS), b256, 0, stream>>>(x, t1, g1, be1, hf, hb);
    k_gemm<128, 128, 1><<<dim3(FFDIM / 128, MROWS / 128), b256, 0, stream>>>(
        hb, w1t, b1, gbf, MROWS, FFDIM, EDIM);
    k_gemm<128, 64, 2><<<dim3(EDIM / 64, MROWS / 128), b256, 0, stream>>>(
        gbf, w2t, b2, t1, MROWS, EDIM, FFDIM);
    k_ln<0><<<dim3(MROWS), b256, 0, stream>>>(hf, t1, g2, be2, out, nullptr);
    (void)in_sizes; (void)n_in; (void)out_size; (void)ws_size;
}